// Round 2
// baseline (1025.410 us; speedup 1.0000x reference)
//
#include <hip/hip_runtime.h>

#define NROWS 1048576
#define D 128
#define S 4096

typedef __bf16 bf16;
typedef __attribute__((ext_vector_type(8))) __bf16 bf16x8;
typedef __attribute__((ext_vector_type(4))) __bf16 bf16x4;
typedef __attribute__((ext_vector_type(4))) float f32x4;

// ---------------------------------------------------------------------------
// Kernel Z: zero xs accumulator in workspace; pre-convert Gamma_W -> bf16
// ---------------------------------------------------------------------------
__global__ __launch_bounds__(256) void k_init(const float* __restrict__ GW,
                                              float* __restrict__ xs,
                                              bf16* __restrict__ gwb) {
    int i = blockIdx.x * 256 + threadIdx.x;
    if (i < S * D) xs[i] = 0.f;
    if (i < D * D) gwb[i] = (bf16)GW[i];
}

// ---------------------------------------------------------------------------
// Kernel A: segment sum, f32x4 (16 B/lane) nontemporal loads. seg_ids sorted
// -> register accumulation, atomics only at segment boundaries.
// Block = 256 threads over 512 rows: thread t owns float4-column (t&31) of
// stream (t>>5); 8 streams interleave rows mod 8. Each load instruction covers
// 2 full rows = 1 KB contiguous.
// ---------------------------------------------------------------------------
#define RPB 512
__global__ __launch_bounds__(256) void k_segsum(const float* __restrict__ x,
                                                const int* __restrict__ sid,
                                                float* __restrict__ xs) {
    __shared__ int ssid[RPB];
    const int t = threadIdx.x;
    const size_t r0 = (size_t)blockIdx.x * RPB;
    ssid[t]       = sid[r0 + t];
    ssid[t + 256] = sid[r0 + t + 256];
    __syncthreads();
    const int c4 = (t & 31) * 4;   // float4 column
    const int st = t >> 5;         // stream 0..7
    f32x4 acc = {0.f, 0.f, 0.f, 0.f};
    int cur = ssid[st];
    for (int i = 0; i < 64; i += 4) {
        f32x4 v[4];
        int   s[4];
#pragma unroll
        for (int u = 0; u < 4; ++u) {
            int rl = (i + u) * 8 + st;
            v[u] = __builtin_nontemporal_load(
                       (const f32x4*)(x + (r0 + rl) * D + c4));
            s[u] = ssid[rl];
        }
#pragma unroll
        for (int u = 0; u < 4; ++u) {
            if (s[u] != cur) {          // uniform per 32-lane half-wave
                atomicAdd(&xs[(size_t)cur * D + c4 + 0], acc[0]);
                atomicAdd(&xs[(size_t)cur * D + c4 + 1], acc[1]);
                atomicAdd(&xs[(size_t)cur * D + c4 + 2], acc[2]);
                atomicAdd(&xs[(size_t)cur * D + c4 + 3], acc[3]);
                acc = (f32x4){0.f, 0.f, 0.f, 0.f};
                cur = s[u];
            }
            acc += v[u];
        }
    }
    atomicAdd(&xs[(size_t)cur * D + c4 + 0], acc[0]);
    atomicAdd(&xs[(size_t)cur * D + c4 + 1], acc[1]);
    atomicAdd(&xs[(size_t)cur * D + c4 + 2], acc[2]);
    atomicAdd(&xs[(size_t)cur * D + c4 + 3], acc[3]);
}

// ---------------------------------------------------------------------------
// Kernel B: v[s][j] = Gamma_b[j] - sum_k xs[s][k] * Lambda_W[j][k]
// (unchanged this round — isolate attribution)
// ---------------------------------------------------------------------------
#define SEGS_PER_BLOCK 8
__global__ __launch_bounds__(128) void k_lambda(const float* __restrict__ xs,
                                                const float* __restrict__ LW,
                                                const float* __restrict__ gb,
                                                float* __restrict__ v) {
    __shared__ float L[128 * 129];
    __shared__ float xrow[128];
    const int t = threadIdx.x;
    for (int i = 0; i < 128; ++i)
        L[i * 129 + t] = LW[i * 128 + t];
    const float bj = gb[t];
    for (int sl = 0; sl < SEGS_PER_BLOCK; ++sl) {
        const int s = blockIdx.x * SEGS_PER_BLOCK + sl;
        __syncthreads();
        xrow[t] = xs[(size_t)s * D + t];
        __syncthreads();
        float acc = 0.f;
#pragma unroll 8
        for (int k = 0; k < 128; ++k)
            acc += xrow[k] * L[t * 129 + k];
        v[(size_t)s * D + t] = bj - acc;
    }
}

// ---------------------------------------------------------------------------
// Kernel C: out[r][j] = sum_k x[r][k]*Gamma[j][k] + v[seg[r]][j]
// bf16 MFMA 16x16x32, tile M=128 x N=128, K=128, 4 waves.
// Gamma (B) NOT staged in LDS — fragments read directly from global (32 KB,
// L2-hot in every XCD). LDS 69->35 KB => 3 blocks/CU. x loads and out stores
// nontemporal (pure stream; keep gwb/v resident in L2).
// ---------------------------------------------------------------------------
__global__ __launch_bounds__(256, 3) void k_main(const float* __restrict__ x,
                                                 const int* __restrict__ sid,
                                                 const bf16* __restrict__ gwb,
                                                 const float* __restrict__ v,
                                                 float* __restrict__ out) {
    __shared__ bf16 As[128 * 136];
    __shared__ int  ssid[128];
    const int t = threadIdx.x;
    const size_t r0 = (size_t)blockIdx.x * 128;

    if (t < 128) ssid[t] = sid[r0 + t];

    // Stage x tile (fp32 -> bf16) -> As. 4096 f32x4 slots, coalesced, deep
    // in-flight burst (16 x 16B per lane).
#pragma unroll
    for (int i = 0; i < 16; ++i) {
        int idx = i * 256 + t;       // slot of 4 floats
        int row = idx >> 5;          // 32 float4 per row
        int c4  = idx & 31;
        f32x4 xv = __builtin_nontemporal_load(
                       (const f32x4*)(x + r0 * D + (size_t)idx * 4));
        bf16x4 bv;
        bv[0] = (bf16)xv[0]; bv[1] = (bf16)xv[1]; bv[2] = (bf16)xv[2]; bv[3] = (bf16)xv[3];
        *(bf16x4*)&As[row * 136 + c4 * 4] = bv;
    }
    __syncthreads();

    const int wave = t >> 6, lane = t & 63;
    const int wm = (wave >> 1) * 64;   // M-half of this wave
    const int wn = (wave & 1) * 64;    // N-half of this wave
    const int lm = lane & 15, quad = lane >> 4;

    f32x4 acc[4][4];
#pragma unroll
    for (int mi = 0; mi < 4; ++mi)
#pragma unroll
        for (int ni = 0; ni < 4; ++ni)
            acc[mi][ni] = (f32x4){0.f, 0.f, 0.f, 0.f};

#pragma unroll
    for (int kb = 0; kb < 128; kb += 32) {
        bf16x8 af[4], bb[4];
#pragma unroll
        for (int ni = 0; ni < 4; ++ni)
            bb[ni] = *(const bf16x8*)(gwb + (size_t)(wn + ni * 16 + lm) * 128
                                          + kb + quad * 8);
#pragma unroll
        for (int mi = 0; mi < 4; ++mi)
            af[mi] = *(const bf16x8*)&As[(wm + mi * 16 + lm) * 136 + kb + quad * 8];
#pragma unroll
        for (int mi = 0; mi < 4; ++mi)
#pragma unroll
            for (int ni = 0; ni < 4; ++ni)
                acc[mi][ni] = __builtin_amdgcn_mfma_f32_16x16x32_bf16(
                    af[mi], bb[ni], acc[mi][ni], 0, 0, 0);
    }

    // Epilogue: C/D layout col = lane&15 (N), row = quad*4 + reg (M).
#pragma unroll
    for (int mi = 0; mi < 4; ++mi) {
        const int rbase = wm + mi * 16 + quad * 4;
#pragma unroll
        for (int reg = 0; reg < 4; ++reg) {
            const int rl = rbase + reg;
            const int s = ssid[rl];
            const float* vrow = v + (size_t)s * D;
            const size_t obase = (r0 + rl) * D;
#pragma unroll
            for (int ni = 0; ni < 4; ++ni) {
                const int j = wn + ni * 16 + lm;
                __builtin_nontemporal_store(acc[mi][ni][reg] + vrow[j],
                                            &out[obase + j]);
            }
        }
    }
}

// ---------------------------------------------------------------------------
extern "C" void kernel_launch(void* const* d_in, const int* in_sizes, int n_in,
                              void* d_out, int out_size, void* d_ws, size_t ws_size,
                              hipStream_t stream) {
    const float* x   = (const float*)d_in[0];
    const int*   sid = (const int*)d_in[1];
    // d_in[2] = num_segments scalar (4096), compile-time constant here
    const float* GW  = (const float*)d_in[3];
    const float* gb  = (const float*)d_in[4];
    const float* LW  = (const float*)d_in[5];
    float* out = (float*)d_out;

    float* xs  = (float*)d_ws;            // [S*D] fp32, 2 MB
    float* v   = xs + S * D;              // [S*D] fp32, 2 MB  (v = Gamma_b - xm)
    bf16*  gwb = (bf16*)(v + S * D);      // [D*D] bf16, 32 KB

    k_init  <<<(S * D + 255) / 256, 256, 0, stream>>>(GW, xs, gwb);
    k_segsum<<<NROWS / RPB,          256, 0, stream>>>(x, sid, xs);
    k_lambda<<<S / SEGS_PER_BLOCK,   128, 0, stream>>>(xs, LW, gb, v);
    k_main  <<<NROWS / 128,          256, 0, stream>>>(x, sid, gwb, v, out);
}